// Round 5
// baseline (557.260 us; speedup 1.0000x reference)
//
#include <hip/hip_runtime.h>
#include <hip/hip_bf16.h>

// ---------------------------------------------------------------------------
// Compile-time construction of the 28x8 DWT composition matrix M:
//   y[k] = sum_j M[k][j] * patch[j],  k = [aa(7), ad(7), dd(7), da(7)]
// exactly matching pywt dwt mode='symmetric' applied twice (n=8 then n=7).
// ---------------------------------------------------------------------------
struct M28x8 { float m[28][8]; };

constexpr double DLO[8] = {-0.010597401784997278, 0.032883011666982945,
                            0.030841381835986965, -0.18703481171888114,
                           -0.02798376941698385,   0.6308807679295904,
                            0.7148465705525415,    0.23037781330885523};
constexpr double DHI[8] = {-0.23037781330885523,   0.7148465705525415,
                           -0.6308807679295904,   -0.02798376941698385,
                            0.18703481171888114,   0.030841381835986965,
                           -0.032883011666982945, -0.010597401784997278};

constexpr void dwt_c(const double* x, int n, double* lo, double* hi) {
    int out_len = (n + 7) / 2;
    for (int i = 0; i < out_len; ++i) {
        double a = 0.0, d = 0.0;
        for (int j = 0; j < 8; ++j) {
            int q = 2 * i + j - 6;
            if (q < 0) q = -q - 1;
            if (q >= n) q = 2 * n - 1 - q;
            a += DLO[7 - j] * x[q];
            d += DHI[7 - j] * x[q];
        }
        lo[i] = a; hi[i] = d;
    }
}

constexpr M28x8 build_M() {
    M28x8 R{};
    for (int j = 0; j < 8; ++j) {
        double x[8] = {0,0,0,0,0,0,0,0};
        x[j] = 1.0;
        double cA[7] = {}, cD[7] = {};
        dwt_c(x, 8, cA, cD);
        double aa[7] = {}, ad[7] = {}, da[7] = {}, dd[7] = {};
        dwt_c(cA, 7, aa, ad);
        dwt_c(cD, 7, da, dd);
        for (int i = 0; i < 7; ++i) {
            R.m[i][j]      = (float)aa[i];
            R.m[7 + i][j]  = (float)ad[i];
            R.m[14 + i][j] = (float)dd[i];   // dd before da in concat
            R.m[21 + i][j] = (float)da[i];
        }
    }
    return R;
}

__constant__ M28x8 g_M = build_M();

// ---------------------------------------------------------------------------
// Wfold[o][c*8+j] = sum_k W[o, c*28+k] * M[k][j]   -> 128*24 = 3072 floats
// (o-major: each lane's 2 rows of 24 are contiguous float4 loads)
// ---------------------------------------------------------------------------
__global__ void wfold_kernel(const float* __restrict__ W, float* __restrict__ Wf) {
    int t = blockIdx.x * blockDim.x + threadIdx.x;
    if (t >= 128 * 24) return;
    int o = t / 24;
    int cj = t - o * 24;
    int c = cj >> 3;
    int j = cj & 7;
    const float* wr = W + o * 84 + c * 28;
    float acc = 0.f;
#pragma unroll
    for (int k = 0; k < 28; ++k) acc += wr[k] * g_M.m[k][j];
    Wf[t] = acc;
}

// ---------------------------------------------------------------------------
// Main kernel (round-5: scalar-pipe x, zero LDS).
//
//   out[b, v*1024 + p, o] = sum_i Wf[o][i] * xw[i]   (xw = 24-float window)
//
// One wave processes one (v, pl) pair per iteration; lanes spread across o.
// The 24-float x-window is then WAVE-UNIFORM: the compiler scalarizes the
// loads to s_load_dword through the scalar cache (all 24 offsets fit the
// 21-bit SMEM immediate off one base: c*409600 B + j*100 B).
//   * zero LDS: no slab staging, no transpose tile, no fences, no barriers.
//     (rounds 0-4 were serially dominated by DS issue / staging machinery)
//   * FMA = v_fmac acc, s_x, v_w (1 SGPR operand) -> VALU does only the
//     32 us FMA floor.
//   * lane owns o = {2*lane, 2*lane+1} -> one global_store_dwordx2 per pair,
//     one contiguous 512 B segment.
//   * 2048 blocks x 4 waves, ~60 VGPR, 0 LDS -> 8 blocks/CU = 32 waves/CU.
//   * exactly 100 pairs per wave (400/block) -> zero imbalance.
//   * K$ locality: v,v+1 share 64 B lines; per-wave window-line set ~13 KB
//     fits 16 KB sL1 -> s_loads mostly K$-hit.
// ---------------------------------------------------------------------------
#define PT 16

__global__ __launch_bounds__(256) void wave_kernel(const float* __restrict__ x,
                                                   const float* __restrict__ Wf,
                                                   float* __restrict__ out) {
    const int tile = blockIdx.x;        // 0..63
    const int b    = blockIdx.y;        // 0..31
    const int t0   = tile * (4 * PT);   // 0,64,...,4032
    const int tid  = threadIdx.x;
    const int lane = tid & 63;
    const int wv   = tid >> 6;          // 0..3

    // per-lane weights: rows o = 2*lane, 2*lane+1 (48 floats, L1/L2-hot)
    float w0[24], w1[24];
    {
        const float4* wp0 = (const float4*)(Wf + (2 * lane) * 24);
        const float4* wp1 = (const float4*)(Wf + (2 * lane + 1) * 24);
#pragma unroll
        for (int q = 0; q < 6; ++q) {
            float4 f0 = wp0[q];
            float4 f1 = wp1[q];
            w0[4*q+0] = f0.x; w0[4*q+1] = f0.y; w0[4*q+2] = f0.z; w0[4*q+3] = f0.w;
            w1[4*q+0] = f1.x; w1[4*q+1] = f1.y; w1[4*q+2] = f1.z; w1[4*q+3] = f1.w;
        }
    }

    const long xrow = (long)(b * 3) * 4096;     // x row base (dwords /25)

    for (int it = 0; it < 100; ++it) {
        const int idx = wv * 100 + it;          // 0..399 (uniform per wave)
        const int v   = idx >> 4;               // 0..24
        const int pl  = idx & 15;               // 0..15
        const int tb  = t0 + 4 * pl;            // window start t

        // wave-uniform 24-float window -> scalar loads
        float xs[24];
        if (tb + 7 <= 4095) {
            // fast path: one base, 24 compile-time immediate offsets
            const float* xb = x + (xrow + tb) * 25 + v;
#pragma unroll
            for (int c = 0; c < 3; ++c)
#pragma unroll
                for (int j = 0; j < 8; ++j)
                    xs[c * 8 + j] = xb[c * 102400 + j * 25];
        } else {
            // edge path (only tile==63 && pl==15): clamp t to 4095 (PAD=4 edge)
#pragma unroll
            for (int c = 0; c < 3; ++c)
#pragma unroll
                for (int j = 0; j < 8; ++j) {
                    int tj = tb + j;
                    if (tj > 4095) tj = 4095;
                    xs[c * 8 + j] = x[(xrow + c * 4096 + tj) * 25 + v];
                }
        }

        float a0 = 0.f, a1 = 0.f;
#pragma unroll
        for (int i = 0; i < 24; ++i) {
            a0 += xs[i] * w0[i];
            a1 += xs[i] * w1[i];
        }

        float2 st = {a0, a1};
        *(float2*)(out + ((long)(b * 25600 + v * 1024 + tile * PT + pl)) * 128
                       + 2 * lane) = st;
    }
}

extern "C" void kernel_launch(void* const* d_in, const int* in_sizes, int n_in,
                              void* d_out, int out_size, void* d_ws, size_t ws_size,
                              hipStream_t stream) {
    const float* x = (const float*)d_in[0];   // (32, 3, 4096, 25) fp32
    const float* W = (const float*)d_in[1];   // (128, 84) fp32
    float* out = (float*)d_out;               // (32, 25600, 128) fp32
    float* Wf  = (float*)d_ws;                // 3072 floats scratch

    hipLaunchKernelGGL(wfold_kernel, dim3(12), dim3(256), 0, stream, W, Wf);
    hipLaunchKernelGGL(wave_kernel, dim3(64, 32), dim3(256), 0, stream, x, Wf, out);
}